// Round 15
// baseline (76.725 us; speedup 1.0000x reference)
//
#include <hip/hip_runtime.h>
#include <math.h>

#define Bdim 32
#define Sdim 2048
#define Hdim 1024

typedef float f4 __attribute__((ext_vector_type(4)));

// ws layout (in floats)
#define OFF_SCORES 0          // B*S = 65536
#define OFF_U      65536      // B*H = 32768
#define OFF_PM     98304      // 2048 per-block maxes
#define OFF_PL     100352     // 2048 per-block sums
#define OFF_TC     102400     // B*2H tanh(concat) = 65536
#define OFF_PACC   167936     // 2048 * 1024 partial contexts
#define OFF_UPART  167936     // aliased: k0/k1 partials (1M floats) dead before k2
// total = 2265088 floats = 9.06 MiB

__device__ __forceinline__ float dot4(float4 a, float4 b) {
    return a.x*b.x + a.y*b.y + a.z*b.z + a.w*b.w;
}

// ---- k0: upart[gc][b][h] = sum_{g in chunk} state[b,g] * Wa[g,h] ----
// grid (8 hc, 32 gc), 128 threads. Wa read EXACTLY ONCE (no per-b redundancy):
// per g, the 128 lanes load 512B contiguous; 32-deep unroll = 32 loads in flight.
__global__ void __launch_bounds__(128) k0_u_partial(
        const float* __restrict__ state, const float* __restrict__ Wa,
        float* __restrict__ upart) {
    __shared__ float st[32][32];            // [b][g within chunk]
    const int hc = blockIdx.x;              // 0..7  (h chunk of 128)
    const int gc = blockIdx.y;              // 0..31 (g chunk of 32)
    const int t  = threadIdx.x;             // 0..127
    for (int i = t; i < 1024; i += 128) {
        int b = i >> 5, g = i & 31;
        st[b][g] = state[b * Hdim + gc * 32 + g];
    }
    __syncthreads();
    float acc[32];
#pragma unroll
    for (int b = 0; b < 32; ++b) acc[b] = 0.f;
    const int h = hc * 128 + t;
#pragma unroll
    for (int g = 0; g < 32; ++g) {          // fully unrolled
        float w = Wa[(size_t)(gc * 32 + g) * Hdim + h];
#pragma unroll
        for (int b = 0; b < 32; ++b) acc[b] += st[b][g] * w;
    }
#pragma unroll
    for (int b = 0; b < 32; ++b)
        upart[((size_t)gc * 32 + b) * Hdim + h] = acc[b];
}

// ---- k1: u = sum over 32 g-chunks of upart (fully unrolled) ----
__global__ void __launch_bounds__(256) k1_u_combine(
        const float* __restrict__ upart, float* __restrict__ u) {
    const int i = blockIdx.x * 256 + threadIdx.x;   // 0..32767 = b*H + h
    float s = 0.f;
#pragma unroll
    for (int gc = 0; gc < 32; ++gc) s += upart[(size_t)gc * 32768 + i];
    u[i] = s;
}

// ---- k2: streaming pass over enc (R12 math), 2048 blocks x 2 waves ----
// 32 rows/block, 16 rows/wave in pairs. Smaller blocks stagger the epilogue
// (sync + LDS combine + pacc write) against other blocks' streaming.
__global__ void __launch_bounds__(128) k2_main(
        const float* __restrict__ enc, const float* __restrict__ u,
        float* __restrict__ scores, float* __restrict__ pm,
        float* __restrict__ pl, float* __restrict__ pacc) {
    const int sc   = blockIdx.x;            // 0..63, 32 rows per block
    const int b    = blockIdx.y;            // 0..31
    const int t    = threadIdx.x;           // 0..127
    const int wv   = t >> 6;                // wave 0..1, 16 rows each
    const int lane = t & 63;

    __shared__ float wm[2], wl[2];
    __shared__ float wacc[2][1024];

    // lane's 16 u values: h = i*256 + lane*4 + j
    float uf[16];
    const float4* u4 = reinterpret_cast<const float4*>(u + (size_t)b * Hdim);
#pragma unroll
    for (int i = 0; i < 4; ++i) {
        float4 v = u4[i * 64 + lane];
        uf[4*i] = v.x; uf[4*i+1] = v.y; uf[4*i+2] = v.z; uf[4*i+3] = v.w;
    }

    float acc[16];
#pragma unroll
    for (int j = 0; j < 16; ++j) acc[j] = 0.f;
    float m = -INFINITY, l = 0.f;

    const int s0 = sc * 32 + wv * 16;
    const f4* base4 =
        reinterpret_cast<const f4*>(enc + ((size_t)b * Sdim + s0) * Hdim);

    for (int g = 0; g < 8; ++g) {           // 8 pairs of rows
        float x[2][16];
#pragma unroll
        for (int k = 0; k < 2; ++k) {
            const f4* row4 = base4 + (size_t)(g * 2 + k) * 256;
#pragma unroll
            for (int i = 0; i < 4; ++i) {
                f4 v = row4[i * 64 + lane];
                x[k][4*i] = v.x; x[k][4*i+1] = v.y; x[k][4*i+2] = v.z; x[k][4*i+3] = v.w;
            }
        }
        float d[2];
#pragma unroll
        for (int k = 0; k < 2; ++k) {
            float dd = 0.f;
#pragma unroll
            for (int j = 0; j < 16; ++j) dd += x[k][j] * uf[j];
            d[k] = dd;
        }
        // 2 concurrent butterflies
#pragma unroll
        for (int off = 32; off >= 1; off >>= 1) {
            d[0] += __shfl_xor(d[0], off, 64);
            d[1] += __shfl_xor(d[1], off, 64);
        }
        if (lane == 0) {
            scores[(size_t)b * Sdim + s0 + g*2 + 0] = d[0];
            scores[(size_t)b * Sdim + s0 + g*2 + 1] = d[1];
        }
        float gm = fmaxf(d[0], d[1]);
        if (gm > m) {                        // wave-uniform, once per pair
            float al = __expf(m - gm);       // exp(-inf)=0 on first pair
#pragma unroll
            for (int j = 0; j < 16; ++j) acc[j] *= al;
            l *= al;
            m = gm;
        }
#pragma unroll
        for (int k = 0; k < 2; ++k) {
            float p = __expf(d[k] - m);
            l += p;
#pragma unroll
            for (int j = 0; j < 16; ++j) acc[j] += p * x[k][j];
        }
    }

    // ---- block-level combine of the 2 wave partials ----
    if (lane == 0) { wm[wv] = m; wl[wv] = l; }
    float4* wa = reinterpret_cast<float4*>(&wacc[wv][0]);
#pragma unroll
    for (int i = 0; i < 4; ++i)
        wa[i * 64 + lane] = make_float4(acc[4*i], acc[4*i+1], acc[4*i+2], acc[4*i+3]);
    __syncthreads();

    const float M  = fmaxf(wm[0], wm[1]);
    const float e0 = __expf(wm[0] - M), e1 = __expf(wm[1] - M);
    const int pidx = b * 64 + sc;
    if (t == 0) {
        pm[pidx] = M;
        pl[pidx] = e0*wl[0] + e1*wl[1];
    }
    // 128 threads cover 1024 floats: 8 per thread (two float4 chunks)
#pragma unroll
    for (int i = 0; i < 2; ++i) {
        const int idx = i * 512 + t * 4;
        const float4 c0 = *reinterpret_cast<const float4*>(&wacc[0][idx]);
        const float4 c1 = *reinterpret_cast<const float4*>(&wacc[1][idx]);
        float4 c;
        c.x = e0*c0.x + e1*c1.x;
        c.y = e0*c0.y + e1*c1.y;
        c.z = e0*c0.z + e1*c1.z;
        c.w = e0*c0.w + e1*c1.w;
        *reinterpret_cast<float4*>(pacc + (size_t)pidx * Hdim + idx) = c;
    }
}

// ---- k3: combine 64 partials per b -> context, tanh(concat), softmax out ----
// grid (4, 32): blockIdx.x = h-quarter, blockIdx.y = b
__global__ void __launch_bounds__(256) k3_combine(
        const float* __restrict__ pm, const float* __restrict__ pl,
        const float* __restrict__ pacc, const float* __restrict__ scores,
        const float* __restrict__ state,
        float* __restrict__ tc, float* __restrict__ sm_out) {
    const int hq = blockIdx.x;              // 0..3
    const int b  = blockIdx.y;
    const int t  = threadIdx.x;
    __shared__ float e[64];
    __shared__ float MS, LS;
    if (t < 64) {
        float mi = pm[b * 64 + t];
        float M = mi;
#pragma unroll
        for (int off = 32; off >= 1; off >>= 1) M = fmaxf(M, __shfl_xor(M, off, 64));
        float ee = __expf(mi - M);
        float Li = ee * pl[b * 64 + t];
#pragma unroll
        for (int off = 32; off >= 1; off >>= 1) Li += __shfl_xor(Li, off, 64);
        e[t] = ee;
        if (t == 0) { MS = M; LS = Li; }
    }
    __syncthreads();
    const float M = MS, invL = 1.f / LS;

    // context for h = hq*256 + t  (8 independent loads in flight)
    const int h = hq * 256 + t;
    float c = 0.f;
#pragma unroll 8
    for (int i = 0; i < 64; ++i)
        c += e[i] * pacc[((size_t)(b * 64 + i)) * Hdim + h];
    tc[(size_t)b * 2048 + h] = tanhf(c * invL);
    tc[(size_t)b * 2048 + 1024 + h] = tanhf(state[(size_t)b * Hdim + h]);

    // softmax_attn output: this block's quarter of rows
#pragma unroll
    for (int i = 0; i < 2; ++i) {
        int s = hq * 512 + i * 256 + t;
        sm_out[(size_t)b * Sdim + s] = __expf(scores[(size_t)b * Sdim + s] - M) * invL;
    }
}

// ---- k4_v4: out[b,o] = relu(tc[b,:] . Wc[o,:] + Wcb[o]) (round-12 version) ----
__global__ void __launch_bounds__(256) k4_out(
        const float* __restrict__ tc, const float* __restrict__ Wc,
        const float* __restrict__ Wcb, float* __restrict__ out) {
    const int bx = blockIdx.x;              // 0..255
    const int o0 = (bx >> 1) * 8;
    const int bh = bx & 1;
    const int t  = threadIdx.x;
    const int wv = t >> 6, lane = t & 63;
    const int b0 = bh * 16 + wv * 4;
    const int kb = lane * 4;                // lane base within each 256-chunk

    f4 a[4][8];
#pragma unroll
    for (int b = 0; b < 4; ++b)
#pragma unroll
        for (int i = 0; i < 8; ++i)
            a[b][i] = *reinterpret_cast<const f4*>(
                tc + (size_t)(b0 + b) * 2048 + i * 256 + kb);

    float p[8][4];
#pragma unroll
    for (int o = 0; o < 8; ++o) {
        f4 w[8];
#pragma unroll
        for (int i = 0; i < 8; ++i)
            w[i] = *reinterpret_cast<const f4*>(
                Wc + (size_t)(o0 + o) * 2048 + i * 256 + kb);
#pragma unroll
        for (int b = 0; b < 4; ++b) {
            float s = 0.f;
#pragma unroll
            for (int i = 0; i < 8; ++i)
                s += w[i].x*a[b][i].x + w[i].y*a[b][i].y
                   + w[i].z*a[b][i].z + w[i].w*a[b][i].w;
            p[o][b] = s;
        }
    }
#pragma unroll
    for (int off = 32; off >= 1; off >>= 1)
#pragma unroll
        for (int o = 0; o < 8; ++o)
#pragma unroll
            for (int b = 0; b < 4; ++b)
                p[o][b] += __shfl_xor(p[o][b], off, 64);

    if (lane == 0) {
#pragma unroll
        for (int o = 0; o < 8; ++o) {
            float bias = Wcb[o0 + o];
#pragma unroll
            for (int b = 0; b < 4; ++b)
                out[(size_t)(b0 + b) * Hdim + o0 + o] = fmaxf(p[o][b] + bias, 0.f);
        }
    }
}

extern "C" void kernel_launch(void* const* d_in, const int* in_sizes, int n_in,
                              void* d_out, int out_size, void* d_ws, size_t ws_size,
                              hipStream_t stream) {
    const float* enc   = (const float*)d_in[0];   // [B,S,H]
    const float* ts    = (const float*)d_in[1];   // [1,B,H]
    const float* Wa    = (const float*)d_in[2];   // [H,H]
    const float* Wc    = (const float*)d_in[3];   // [H,2H]
    const float* Wcb   = (const float*)d_in[4];   // [H]
    float* out = (float*)d_out;                   // [B*H output | B*S softmax]
    float* ws  = (float*)d_ws;

    float* scores = ws + OFF_SCORES;
    float* u      = ws + OFF_U;
    float* pm     = ws + OFF_PM;
    float* pl     = ws + OFF_PL;
    float* tc     = ws + OFF_TC;
    float* pacc   = ws + OFF_PACC;
    float* upart  = ws + OFF_UPART;   // aliases pacc (dead before k2 writes it)

    k0_u_partial<<<dim3(8, 32), 128, 0, stream>>>(ts, Wa, upart);
    k1_u_combine<<<dim3(128), 256, 0, stream>>>(upart, u);
    k2_main<<<dim3(64, 32), 128, 0, stream>>>(enc, u, scores, pm, pl, pacc);
    k3_combine<<<dim3(4, 32), 256, 0, stream>>>(pm, pl, pacc, scores, ts,
                                                tc, out + Bdim * Hdim);
    k4_out<<<dim3(256), 256, 0, stream>>>(tc, Wc, Wcb, out);
}

// Round 16
// 72.781 us; speedup vs baseline: 1.0542x; 1.0542x over previous
//
#include <hip/hip_runtime.h>
#include <math.h>

#define Bdim 32
#define Sdim 2048
#define Hdim 1024

typedef float f4 __attribute__((ext_vector_type(4)));

// ws layout (in floats) — identical to round 12
#define OFF_SCORES 0          // B*S = 65536
#define OFF_U      65536      // B*H = 32768
#define OFF_PM     98304      // 1024 per-block maxes
#define OFF_PL     99328      // 1024 per-block sums
#define OFF_TC     100352     // B*2H tanh(concat) = 65536
#define OFF_PACC   165888     // 1024 * 1024 partial contexts
#define OFF_UPART  165888     // aliased: k0/k1 partials (1M floats) dead before k2
// total ~= 4.86 MiB

__device__ __forceinline__ float dot4(float4 a, float4 b) {
    return a.x*b.x + a.y*b.y + a.z*b.z + a.w*b.w;
}

// ---- k0: upart[gc][b][h] = sum_{g in chunk} state[b,g] * Wa[g,h] ----
// grid (8 hc, 32 gc), 128 threads. Wa read EXACTLY ONCE (no per-b redundancy).
__global__ void __launch_bounds__(128) k0_u_partial(
        const float* __restrict__ state, const float* __restrict__ Wa,
        float* __restrict__ upart) {
    __shared__ float st[32][32];            // [b][g within chunk]
    const int hc = blockIdx.x;              // 0..7  (h chunk of 128)
    const int gc = blockIdx.y;              // 0..31 (g chunk of 32)
    const int t  = threadIdx.x;             // 0..127
    for (int i = t; i < 1024; i += 128) {
        int b = i >> 5, g = i & 31;
        st[b][g] = state[b * Hdim + gc * 32 + g];
    }
    __syncthreads();
    float acc[32];
#pragma unroll
    for (int b = 0; b < 32; ++b) acc[b] = 0.f;
    const int h = hc * 128 + t;
#pragma unroll
    for (int g = 0; g < 32; ++g) {          // fully unrolled: 32 loads in flight
        float w = Wa[(size_t)(gc * 32 + g) * Hdim + h];
#pragma unroll
        for (int b = 0; b < 32; ++b) acc[b] += st[b][g] * w;
    }
#pragma unroll
    for (int b = 0; b < 32; ++b)
        upart[((size_t)gc * 32 + b) * Hdim + h] = acc[b];
}

// ---- k1: u = sum over 32 g-chunks of upart (fully unrolled) ----
__global__ void __launch_bounds__(256) k1_u_combine(
        const float* __restrict__ upart, float* __restrict__ u) {
    const int i = blockIdx.x * 256 + threadIdx.x;   // 0..32767 = b*H + h
    float s = 0.f;
#pragma unroll
    for (int gc = 0; gc < 32; ++gc) s += upart[(size_t)gc * 32768 + i];
    u[i] = s;
}

// ---- k2: single streaming pass over enc (round-12 EXACT: plain loads,
// online softmax, 1024 blocks (32 s-chunks x 32 b), 4 waves, pairs) ----
__global__ void __launch_bounds__(256) k2_main(
        const float* __restrict__ enc, const float* __restrict__ u,
        float* __restrict__ scores, float* __restrict__ pm,
        float* __restrict__ pl, float* __restrict__ pacc) {
    const int sc   = blockIdx.x;            // 0..31, 64 rows per block
    const int b    = blockIdx.y;            // 0..31
    const int t    = threadIdx.x;
    const int wv   = t >> 6;                // wave 0..3, 16 rows each
    const int lane = t & 63;

    __shared__ float wm[4], wl[4];
    __shared__ float wacc[4][1024];

    // lane's 16 u values: h = i*256 + lane*4 + j
    float uf[16];
    const float4* u4 = reinterpret_cast<const float4*>(u + (size_t)b * Hdim);
#pragma unroll
    for (int i = 0; i < 4; ++i) {
        float4 v = u4[i * 64 + lane];
        uf[4*i] = v.x; uf[4*i+1] = v.y; uf[4*i+2] = v.z; uf[4*i+3] = v.w;
    }

    float acc[16];
#pragma unroll
    for (int j = 0; j < 16; ++j) acc[j] = 0.f;
    float m = -INFINITY, l = 0.f;

    const int s0 = sc * 64 + wv * 16;
    const f4* base4 =
        reinterpret_cast<const f4*>(enc + ((size_t)b * Sdim + s0) * Hdim);

    for (int g = 0; g < 8; ++g) {           // 8 pairs of rows
        float x[2][16];
#pragma unroll
        for (int k = 0; k < 2; ++k) {
            const f4* row4 = base4 + (size_t)(g * 2 + k) * 256;
#pragma unroll
            for (int i = 0; i < 4; ++i) {
                f4 v = row4[i * 64 + lane];
                x[k][4*i] = v.x; x[k][4*i+1] = v.y; x[k][4*i+2] = v.z; x[k][4*i+3] = v.w;
            }
        }
        float d[2];
#pragma unroll
        for (int k = 0; k < 2; ++k) {
            float dd = 0.f;
#pragma unroll
            for (int j = 0; j < 16; ++j) dd += x[k][j] * uf[j];
            d[k] = dd;
        }
#pragma unroll
        for (int off = 32; off >= 1; off >>= 1) {
            d[0] += __shfl_xor(d[0], off, 64);
            d[1] += __shfl_xor(d[1], off, 64);
        }
        if (lane == 0) {
            scores[(size_t)b * Sdim + s0 + g*2 + 0] = d[0];
            scores[(size_t)b * Sdim + s0 + g*2 + 1] = d[1];
        }
        float gm = fmaxf(d[0], d[1]);
        if (gm > m) {                        // wave-uniform, once per pair
            float al = __expf(m - gm);       // exp(-inf)=0 on first pair
#pragma unroll
            for (int j = 0; j < 16; ++j) acc[j] *= al;
            l *= al;
            m = gm;
        }
#pragma unroll
        for (int k = 0; k < 2; ++k) {
            float p = __expf(d[k] - m);
            l += p;
#pragma unroll
            for (int j = 0; j < 16; ++j) acc[j] += p * x[k][j];
        }
    }

    // ---- block-level combine of the 4 wave partials ----
    if (lane == 0) { wm[wv] = m; wl[wv] = l; }
    float4* wa = reinterpret_cast<float4*>(&wacc[wv][0]);
#pragma unroll
    for (int i = 0; i < 4; ++i)
        wa[i * 64 + lane] = make_float4(acc[4*i], acc[4*i+1], acc[4*i+2], acc[4*i+3]);
    __syncthreads();

    const float M  = fmaxf(fmaxf(wm[0], wm[1]), fmaxf(wm[2], wm[3]));
    const float e0 = __expf(wm[0] - M), e1 = __expf(wm[1] - M);
    const float e2 = __expf(wm[2] - M), e3 = __expf(wm[3] - M);
    const int pidx = b * 32 + sc;
    if (t == 0) {
        pm[pidx] = M;
        pl[pidx] = e0*wl[0] + e1*wl[1] + e2*wl[2] + e3*wl[3];
    }
    const float4 c0 = *reinterpret_cast<const float4*>(&wacc[0][t * 4]);
    const float4 c1 = *reinterpret_cast<const float4*>(&wacc[1][t * 4]);
    const float4 c2 = *reinterpret_cast<const float4*>(&wacc[2][t * 4]);
    const float4 c3 = *reinterpret_cast<const float4*>(&wacc[3][t * 4]);
    float4 c;
    c.x = e0*c0.x + e1*c1.x + e2*c2.x + e3*c3.x;
    c.y = e0*c0.y + e1*c1.y + e2*c2.y + e3*c3.y;
    c.z = e0*c0.z + e1*c1.z + e2*c2.z + e3*c3.z;
    c.w = e0*c0.w + e1*c1.w + e2*c2.w + e3*c3.w;
    *reinterpret_cast<float4*>(pacc + (size_t)pidx * Hdim + t * 4) = c;
}

// ---- k3: combine partials -> context, tanh(concat), softmax output ----
// (round-12 exact) grid (4, 32): blockIdx.x = h-quarter, blockIdx.y = b
__global__ void __launch_bounds__(256) k3_combine(
        const float* __restrict__ pm, const float* __restrict__ pl,
        const float* __restrict__ pacc, const float* __restrict__ scores,
        const float* __restrict__ state,
        float* __restrict__ tc, float* __restrict__ sm_out) {
    const int hq = blockIdx.x;              // 0..3
    const int b  = blockIdx.y;
    const int t  = threadIdx.x;
    __shared__ float e[32];
    __shared__ float MS, LS;
    if (t < 32) {
        float mi = pm[b * 32 + t];
        float M = mi;
#pragma unroll
        for (int off = 16; off >= 1; off >>= 1) M = fmaxf(M, __shfl_xor(M, off, 64));
        float ee = __expf(mi - M);
        float Li = ee * pl[b * 32 + t];
#pragma unroll
        for (int off = 16; off >= 1; off >>= 1) Li += __shfl_xor(Li, off, 64);
        e[t] = ee;
        if (t == 0) { MS = M; LS = Li; }
    }
    __syncthreads();
    const float M = MS, invL = 1.f / LS;

    const int h = hq * 256 + t;
    float c = 0.f;
#pragma unroll 8
    for (int i = 0; i < 32; ++i)
        c += e[i] * pacc[((size_t)(b * 32 + i)) * Hdim + h];
    tc[(size_t)b * 2048 + h] = tanhf(c * invL);
    tc[(size_t)b * 2048 + 1024 + h] = tanhf(state[(size_t)b * Hdim + h]);

#pragma unroll
    for (int i = 0; i < 2; ++i) {
        int s = hq * 512 + i * 256 + t;
        sm_out[(size_t)b * Sdim + s] = __expf(scores[(size_t)b * Sdim + s] - M) * invL;
    }
}

// ---- k4_v4: out[b,o] = relu(tc[b,:] . Wc[o,:] + Wcb[o]) (round-12 exact) ----
__global__ void __launch_bounds__(256) k4_out(
        const float* __restrict__ tc, const float* __restrict__ Wc,
        const float* __restrict__ Wcb, float* __restrict__ out) {
    const int bx = blockIdx.x;              // 0..255
    const int o0 = (bx >> 1) * 8;
    const int bh = bx & 1;
    const int t  = threadIdx.x;
    const int wv = t >> 6, lane = t & 63;
    const int b0 = bh * 16 + wv * 4;
    const int kb = lane * 4;                // lane base within each 256-chunk

    f4 a[4][8];
#pragma unroll
    for (int b = 0; b < 4; ++b)
#pragma unroll
        for (int i = 0; i < 8; ++i)
            a[b][i] = *reinterpret_cast<const f4*>(
                tc + (size_t)(b0 + b) * 2048 + i * 256 + kb);

    float p[8][4];
#pragma unroll
    for (int o = 0; o < 8; ++o) {
        f4 w[8];
#pragma unroll
        for (int i = 0; i < 8; ++i)
            w[i] = *reinterpret_cast<const f4*>(
                Wc + (size_t)(o0 + o) * 2048 + i * 256 + kb);
#pragma unroll
        for (int b = 0; b < 4; ++b) {
            float s = 0.f;
#pragma unroll
            for (int i = 0; i < 8; ++i)
                s += w[i].x*a[b][i].x + w[i].y*a[b][i].y
                   + w[i].z*a[b][i].z + w[i].w*a[b][i].w;
            p[o][b] = s;
        }
    }
#pragma unroll
    for (int off = 32; off >= 1; off >>= 1)
#pragma unroll
        for (int o = 0; o < 8; ++o)
#pragma unroll
            for (int b = 0; b < 4; ++b)
                p[o][b] += __shfl_xor(p[o][b], off, 64);

    if (lane == 0) {
#pragma unroll
        for (int o = 0; o < 8; ++o) {
            float bias = Wcb[o0 + o];
#pragma unroll
            for (int b = 0; b < 4; ++b)
                out[(size_t)(b0 + b) * Hdim + o0 + o] = fmaxf(p[o][b] + bias, 0.f);
        }
    }
}

extern "C" void kernel_launch(void* const* d_in, const int* in_sizes, int n_in,
                              void* d_out, int out_size, void* d_ws, size_t ws_size,
                              hipStream_t stream) {
    const float* enc   = (const float*)d_in[0];   // [B,S,H]
    const float* ts    = (const float*)d_in[1];   // [1,B,H]
    const float* Wa    = (const float*)d_in[2];   // [H,H]
    const float* Wc    = (const float*)d_in[3];   // [H,2H]
    const float* Wcb   = (const float*)d_in[4];   // [H]
    float* out = (float*)d_out;                   // [B*H output | B*S softmax]
    float* ws  = (float*)d_ws;

    float* scores = ws + OFF_SCORES;
    float* u      = ws + OFF_U;
    float* pm     = ws + OFF_PM;
    float* pl     = ws + OFF_PL;
    float* tc     = ws + OFF_TC;
    float* pacc   = ws + OFF_PACC;
    float* upart  = ws + OFF_UPART;   // aliases pacc (dead before k2 writes it)

    k0_u_partial<<<dim3(8, 32), 128, 0, stream>>>(ts, Wa, upart);
    k1_u_combine<<<dim3(128), 256, 0, stream>>>(upart, u);
    k2_main<<<dim3(32, 32), 256, 0, stream>>>(enc, u, scores, pm, pl, pacc);
    k3_combine<<<dim3(4, 32), 256, 0, stream>>>(pm, pl, pacc, scores, ts,
                                                tc, out + Bdim * Hdim);
    k4_out<<<dim3(256), 256, 0, stream>>>(tc, Wc, Wcb, out);
}

// Round 17
// 71.655 us; speedup vs baseline: 1.0708x; 1.0157x over previous
//
#include <hip/hip_runtime.h>
#include <math.h>

#define Bdim 32
#define Sdim 2048
#define Hdim 1024

typedef float f4 __attribute__((ext_vector_type(4)));

// ws layout (in floats)
#define OFF_SCORES 0          // B*S = 65536
#define OFF_U      65536      // B*H = 32768
#define OFF_PM     98304      // 1024 per-block maxes
#define OFF_PL     99328      // 1024 per-block sums
#define OFF_TC     100352     // B*2H tanh(concat) = 65536
#define OFF_PACC   165888     // 1024 * 1024 partial contexts
// total ~= 4.86 MiB

__device__ __forceinline__ float dot4(float4 a, float4 b) {
    return a.x*b.x + a.y*b.y + a.z*b.z + a.w*b.w;
}

// ---- k01: u[b,h] = sum_g state[b,g] * Wa[g,h] ----
__global__ void __launch_bounds__(512) k01_u(
        const float* __restrict__ state, const float* __restrict__ Wa,
        float* __restrict__ u) {
    const int hc = blockIdx.x;              // 0..7
    const int b  = blockIdx.y;              // 0..31
    const int t  = threadIdx.x;
    __shared__ float st[1024];
    __shared__ float red[512];
    if (t < 256)
        reinterpret_cast<float4*>(st)[t] =
            reinterpret_cast<const float4*>(state + (size_t)b * Hdim)[t];
    __syncthreads();

    const int h  = hc * 128 + (t & 127);
    const int g0 = (t >> 7) * 256;          // 0,256,512,768
    const float* wp = Wa + (size_t)g0 * Hdim + h;
    float acc = 0.f;
#pragma unroll 32
    for (int g = 0; g < 256; ++g)
        acc += st[g0 + g] * wp[(size_t)g * Hdim];
    red[t] = acc;
    __syncthreads();
    if (t < 128)
        u[(size_t)b * Hdim + h] = red[t] + red[t + 128] + red[t + 256] + red[t + 384];
}

// ---- k2: single streaming pass over enc (plain loads -> L3-allocating) ----
// 1024 blocks (32 s-chunks x 32 b), 4 waves/block, 16 rows/wave in pairs.
__global__ void __launch_bounds__(256) k2_main(
        const float* __restrict__ enc, const float* __restrict__ u,
        float* __restrict__ scores, float* __restrict__ pm,
        float* __restrict__ pl, float* __restrict__ pacc) {
    const int sc   = blockIdx.x;            // 0..31, 64 rows per block
    const int b    = blockIdx.y;            // 0..31
    const int t    = threadIdx.x;
    const int wv   = t >> 6;                // wave 0..3, 16 rows each
    const int lane = t & 63;

    __shared__ float wm[4], wl[4];
    __shared__ float wacc[4][1024];

    // lane's 16 u values: h = i*256 + lane*4 + j
    float uf[16];
    const float4* u4 = reinterpret_cast<const float4*>(u + (size_t)b * Hdim);
#pragma unroll
    for (int i = 0; i < 4; ++i) {
        float4 v = u4[i * 64 + lane];
        uf[4*i] = v.x; uf[4*i+1] = v.y; uf[4*i+2] = v.z; uf[4*i+3] = v.w;
    }

    float acc[16];
#pragma unroll
    for (int j = 0; j < 16; ++j) acc[j] = 0.f;
    float m = -INFINITY, l = 0.f;

    const int s0 = sc * 64 + wv * 16;
    const f4* base4 =
        reinterpret_cast<const f4*>(enc + ((size_t)b * Sdim + s0) * Hdim);

    for (int g = 0; g < 8; ++g) {           // 8 pairs of rows
        float x[2][16];
#pragma unroll
        for (int k = 0; k < 2; ++k) {
            const f4* row4 = base4 + (size_t)(g * 2 + k) * 256;
#pragma unroll
            for (int i = 0; i < 4; ++i) {
                f4 v = row4[i * 64 + lane];
                x[k][4*i] = v.x; x[k][4*i+1] = v.y; x[k][4*i+2] = v.z; x[k][4*i+3] = v.w;
            }
        }
        float d[2];
#pragma unroll
        for (int k = 0; k < 2; ++k) {
            float dd = 0.f;
#pragma unroll
            for (int j = 0; j < 16; ++j) dd += x[k][j] * uf[j];
            d[k] = dd;
        }
#pragma unroll
        for (int off = 32; off >= 1; off >>= 1) {
            d[0] += __shfl_xor(d[0], off, 64);
            d[1] += __shfl_xor(d[1], off, 64);
        }
        if (lane == 0) {
            scores[(size_t)b * Sdim + s0 + g*2 + 0] = d[0];
            scores[(size_t)b * Sdim + s0 + g*2 + 1] = d[1];
        }
        float gm = fmaxf(d[0], d[1]);
        if (gm > m) {                        // wave-uniform, once per pair
            float al = __expf(m - gm);       // exp(-inf)=0 on first pair
#pragma unroll
            for (int j = 0; j < 16; ++j) acc[j] *= al;
            l *= al;
            m = gm;
        }
#pragma unroll
        for (int k = 0; k < 2; ++k) {
            float p = __expf(d[k] - m);
            l += p;
#pragma unroll
            for (int j = 0; j < 16; ++j) acc[j] += p * x[k][j];
        }
    }

    // ---- block-level combine of the 4 wave partials ----
    if (lane == 0) { wm[wv] = m; wl[wv] = l; }
    float4* wa = reinterpret_cast<float4*>(&wacc[wv][0]);
#pragma unroll
    for (int i = 0; i < 4; ++i)
        wa[i * 64 + lane] = make_float4(acc[4*i], acc[4*i+1], acc[4*i+2], acc[4*i+3]);
    __syncthreads();

    const float M  = fmaxf(fmaxf(wm[0], wm[1]), fmaxf(wm[2], wm[3]));
    const float e0 = __expf(wm[0] - M), e1 = __expf(wm[1] - M);
    const float e2 = __expf(wm[2] - M), e3 = __expf(wm[3] - M);
    const int pidx = b * 32 + sc;
    if (t == 0) {
        pm[pidx] = M;
        pl[pidx] = e0*wl[0] + e1*wl[1] + e2*wl[2] + e3*wl[3];
    }
    const float4 c0 = *reinterpret_cast<const float4*>(&wacc[0][t * 4]);
    const float4 c1 = *reinterpret_cast<const float4*>(&wacc[1][t * 4]);
    const float4 c2 = *reinterpret_cast<const float4*>(&wacc[2][t * 4]);
    const float4 c3 = *reinterpret_cast<const float4*>(&wacc[3][t * 4]);
    float4 c;
    c.x = e0*c0.x + e1*c1.x + e2*c2.x + e3*c3.x;
    c.y = e0*c0.y + e1*c1.y + e2*c2.y + e3*c3.y;
    c.z = e0*c0.z + e1*c1.z + e2*c2.z + e3*c3.z;
    c.w = e0*c0.w + e1*c1.w + e2*c2.w + e3*c3.w;
    *reinterpret_cast<float4*>(pacc + (size_t)pidx * Hdim + t * 4) = c;
}

// ---- k3: combine partials -> context, tanh(concat), softmax output ----
__global__ void __launch_bounds__(256) k3_combine(
        const float* __restrict__ pm, const float* __restrict__ pl,
        const float* __restrict__ pacc, const float* __restrict__ scores,
        const float* __restrict__ state,
        float* __restrict__ tc, float* __restrict__ sm_out) {
    const int hq = blockIdx.x;              // 0..3
    const int b  = blockIdx.y;
    const int t  = threadIdx.x;
    __shared__ float e[32];
    __shared__ float MS, LS;
    if (t < 32) {
        float mi = pm[b * 32 + t];
        float M = mi;
#pragma unroll
        for (int off = 16; off >= 1; off >>= 1) M = fmaxf(M, __shfl_xor(M, off, 64));
        float ee = __expf(mi - M);
        float Li = ee * pl[b * 32 + t];
#pragma unroll
        for (int off = 16; off >= 1; off >>= 1) Li += __shfl_xor(Li, off, 64);
        e[t] = ee;
        if (t == 0) { MS = M; LS = Li; }
    }
    __syncthreads();
    const float M = MS, invL = 1.f / LS;

    const int h = hq * 256 + t;
    float c = 0.f;
#pragma unroll 8
    for (int i = 0; i < 32; ++i)
        c += e[i] * pacc[((size_t)(b * 32 + i)) * Hdim + h];
    tc[(size_t)b * 2048 + h] = tanhf(c * invL);
    tc[(size_t)b * 2048 + 1024 + h] = tanhf(state[(size_t)b * Hdim + h]);

#pragma unroll
    for (int i = 0; i < 2; ++i) {
        int s = hq * 512 + i * 256 + t;
        sm_out[(size_t)b * Sdim + s] = __expf(scores[(size_t)b * Sdim + s] - M) * invL;
    }
}

// ---- k4_v4: out[b,o] = relu(tc[b,:] . Wc[o,:] + Wcb[o]) ----
// grid 256 = (128 o-octets) x (2 b-halves); wave owns 4 b rows in regs;
// loops 8 o; NO LDS, NO syncthreads; one 6-stage butterfly over 32 values.
__global__ void __launch_bounds__(256) k4_out(
        const float* __restrict__ tc, const float* __restrict__ Wc,
        const float* __restrict__ Wcb, float* __restrict__ out) {
    const int bx = blockIdx.x;              // 0..255
    const int o0 = (bx >> 1) * 8;
    const int bh = bx & 1;
    const int t  = threadIdx.x;
    const int wv = t >> 6, lane = t & 63;
    const int b0 = bh * 16 + wv * 4;
    const int kb = lane * 4;                // lane base within each 256-chunk

    f4 a[4][8];
#pragma unroll
    for (int b = 0; b < 4; ++b)
#pragma unroll
        for (int i = 0; i < 8; ++i)
            a[b][i] = *reinterpret_cast<const f4*>(
                tc + (size_t)(b0 + b) * 2048 + i * 256 + kb);

    float p[8][4];
#pragma unroll
    for (int o = 0; o < 8; ++o) {
        f4 w[8];
#pragma unroll
        for (int i = 0; i < 8; ++i)
            w[i] = *reinterpret_cast<const f4*>(
                Wc + (size_t)(o0 + o) * 2048 + i * 256 + kb);
#pragma unroll
        for (int b = 0; b < 4; ++b) {
            float s = 0.f;
#pragma unroll
            for (int i = 0; i < 8; ++i)
                s += w[i].x*a[b][i].x + w[i].y*a[b][i].y
                   + w[i].z*a[b][i].z + w[i].w*a[b][i].w;
            p[o][b] = s;
        }
    }
#pragma unroll
    for (int off = 32; off >= 1; off >>= 1)
#pragma unroll
        for (int o = 0; o < 8; ++o)
#pragma unroll
            for (int b = 0; b < 4; ++b)
                p[o][b] += __shfl_xor(p[o][b], off, 64);

    if (lane == 0) {
#pragma unroll
        for (int o = 0; o < 8; ++o) {
            float bias = Wcb[o0 + o];
#pragma unroll
            for (int b = 0; b < 4; ++b)
                out[(size_t)(b0 + b) * Hdim + o0 + o] = fmaxf(p[o][b] + bias, 0.f);
        }
    }
}

extern "C" void kernel_launch(void* const* d_in, const int* in_sizes, int n_in,
                              void* d_out, int out_size, void* d_ws, size_t ws_size,
                              hipStream_t stream) {
    const float* enc   = (const float*)d_in[0];   // [B,S,H]
    const float* ts    = (const float*)d_in[1];   // [1,B,H]
    const float* Wa    = (const float*)d_in[2];   // [H,H]
    const float* Wc    = (const float*)d_in[3];   // [H,2H]
    const float* Wcb   = (const float*)d_in[4];   // [H]
    float* out = (float*)d_out;                   // [B*H output | B*S softmax]
    float* ws  = (float*)d_ws;

    float* scores = ws + OFF_SCORES;
    float* u      = ws + OFF_U;
    float* pm     = ws + OFF_PM;
    float* pl     = ws + OFF_PL;
    float* tc     = ws + OFF_TC;
    float* pacc   = ws + OFF_PACC;

    k01_u<<<dim3(8, 32), 512, 0, stream>>>(ts, Wa, u);
    k2_main<<<dim3(32, 32), 256, 0, stream>>>(enc, u, scores, pm, pl, pacc);
    k3_combine<<<dim3(4, 32), 256, 0, stream>>>(pm, pl, pacc, scores, ts,
                                                tc, out + Bdim * Hdim);
    k4_out<<<dim3(256), 256, 0, stream>>>(tc, Wc, Wcb, out);
}